// Round 17
// baseline (58.272 us; speedup 1.0000x reference)
//
#include <hip/hip_runtime.h>

// VanillaGNN via MFMA: B=262144 graphs, N=8 nodes, DIN=3, DH=32, DOUT=1.
// Round-16 base (35.2us) + ONE line: __launch_bounds__(256,4).
// Revised model: with (256,2) the allocator gets a 256-reg/wave envelope and
// parks the AGPR block high (accum_offset) -> descriptor in the 256-bin ->
// 2 waves/SIMD no matter that live VGPR=68. Live set is now ~84 total, so
// the 128-reg envelope fits WITHOUT spill (unlike r9/r12 where it didn't).
// FETCH_SIZE ~12.3MB is the spill canary; absmax must stay exactly 1.2207e-4.
// Chain per wave (4 graphs = 32 node-rows):
//   y = A@x (24 fma) -> L1: P = W1split @ ysplit + b1 (2 kappa-packed MFMA,
//   relu) -> GEMM1: t = bf16(h1) @ bf16(W2) (2 MFMA; pi both sides) ->
//   AGG: h2T = bf16(tT) @ bf16(A32T) (2 MFMA) -> in-register Wout reduction.
// Precision ledger (all measured-free, absmax pinned at 1.2207e-4 = grid floor):
//   tlo (r12/13), w2lo+a32lo (r15), plo (r16).
// Verified layouts (gfx950 mfma_f32_32x32x16_bf16, rounds 3-16):
//   A: lane row=l&31, k=s*16+8*(l>>5)+j   B: col=l&31, same k
//   C/D: col=l&31, row=(reg&3)+8*(reg>>2)+4*(l>>5)
// pi(kk) = rr(kk) = (kk&3)+8*(kk>>2)+4q  (logical index of reg kk).

typedef __bf16 bf16x8 __attribute__((ext_vector_type(8)));
typedef float  f32x16 __attribute__((ext_vector_type(16)));

#define GPT 16  // graphs per block tile (4 waves x 4 graphs)

__global__ __launch_bounds__(256, 4) void gnn_kernel(
    const float* __restrict__ x,       // [B,8,3]
    const int* __restrict__ ei,        // [2,32] int32
    const float* __restrict__ W1,      // [3,32]
    const float* __restrict__ b1,      // [32]
    const float* __restrict__ W2,      // [32,32]
    const float* __restrict__ b2,      // [32]
    const float* __restrict__ Wout,    // [32]
    const float* __restrict__ bout,    // [1]
    float* __restrict__ out,           // [B]
    int B, int ntiles)
{
    __shared__ float As[64];           // A[n][m] (n=dst)
    __shared__ float degs[8], dinvs[8];
    __shared__ float W1s[96], b1s[32], W2s[1024], b2s[32], Wouts[32];
    __shared__ float xs[2][GPT * 24];  // double-buffered [g][8][3]

    const int tid = threadIdx.x;

    // ---- stage weights / build A (once per block) ----
    if (tid < 96) W1s[tid] = W1[tid];
    if (tid < 64) As[tid] = 0.0f;
    if (tid < 32) { b1s[tid] = b1[tid]; b2s[tid] = b2[tid]; Wouts[tid] = Wout[tid]; }
    if (tid < 8)  degs[tid] = 1.0f;
    for (int i = tid; i < 1024; i += 256) W2s[i] = W2[i];
    __syncthreads();
    if (tid < 32) { int d = ei[32 + tid]; atomicAdd(&degs[d], 1.0f); }
    __syncthreads();
    if (tid < 8) dinvs[tid] = 1.0f / sqrtf(degs[tid]);
    __syncthreads();
    if (tid < 32) {
        int s = ei[tid], d = ei[32 + tid];
        atomicAdd(&As[d * 8 + s], dinvs[s] * dinvs[d]);
    } else if (tid < 40) {
        int n = tid - 32;
        atomicAdd(&As[n * 8 + n], dinvs[n] * dinvs[n]);
    }
    __syncthreads();

    // ---- per-lane constants ----
    const int lane = tid & 63;
    const int wv   = tid >> 6;    // wave 0..3
    const int r    = lane & 31;
    const int q    = lane >> 5;   // k-half / row-half selector
    const int n8   = r & 7;       // node within graph
    const int gl   = r >> 3;      // graph within wave
    const int g    = wv * 4 + gl; // block-local graph

    float arow[8];
    #pragma unroll
    for (int m = 0; m < 8; m++) arow[m] = As[n8 * 8 + m];

    // W1^T A-frags, kappa-packed: slots 0-2 = W1[j][r] (hi step0 / lo step1),
    // slot 3 = b1[r] (hi step0 / lo step1; paired with B slot3 = q?0:1)
    bf16x8 w1Ahi, w1Alo;
    #pragma unroll
    for (int j = 0; j < 8; j++) { w1Ahi[j] = (__bf16)0.0f; w1Alo[j] = (__bf16)0.0f; }
    #pragma unroll
    for (int j = 0; j < 3; j++) {
        float v = W1s[j * 32 + r];
        __bf16 h = (__bf16)v;
        w1Ahi[j] = h; w1Alo[j] = (__bf16)(v - (float)h);
    }
    {
        float v = b1s[r];
        __bf16 h = (__bf16)v;
        w1Ahi[3] = h; w1Alo[3] = (__bf16)(v - (float)h);
    }

    // W2 B-frags in pi-order (hi only): slot (s,j), kk=8s+j ->
    //   hidden-in rr(kk) = (kk&3)+8*(kk>>2)+4q ; value bf16(W2[rr(kk)][r])
    bf16x8 w2hi[2];
    #pragma unroll
    for (int s = 0; s < 2; s++) {
        #pragma unroll
        for (int j = 0; j < 8; j++) {
            int kk = 8 * s + j;
            int hid = (kk & 3) + 8 * (kk >> 2) + 4 * q;
            w2hi[s][j] = (__bf16)W2s[hid * 32 + r];
        }
    }
    // A32T B-frags in pi-order (hi only): slot (s,j), kk=8s+j
    //   -> node (kk&3)+4q of graph kk>>2, gated to own graph
    bf16x8 a32hi[2];
    #pragma unroll
    for (int s = 0; s < 2; s++) {
        #pragma unroll
        for (int j = 0; j < 8; j++) {
            int kk = 8 * s + j;
            float v = ((kk >> 2) == gl) ? arow[(kk & 3) + 4 * q] : 0.0f;
            a32hi[s][j] = (__bf16)v;
        }
    }
    // epilogue per-reg constants: reg k holds hidden row hk = rr(k)
    float b2r[16], woutr[16];
    #pragma unroll
    for (int k = 0; k < 16; k++) {
        int hk = (k & 3) + 8 * (k >> 2) + 4 * q;
        b2r[k] = b2s[hk]; woutr[k] = Wouts[hk];
    }
    const float boutv = bout[0];

    // ---- x prefetch (tile 0) ----
    const float4* x4 = reinterpret_cast<const float4*>(x);
    float4 nxt;
    if (tid < 96 && blockIdx.x < ntiles)
        nxt = x4[(long long)blockIdx.x * 96 + tid];
    int buf = 0;

    // ---- tile loop: 1 barrier/tile; prefetch issued after the barrier ----
    for (int tile = blockIdx.x; tile < ntiles; tile += gridDim.x) {
        const long long gbase = (long long)tile * GPT;
        if (tid < 96) *reinterpret_cast<float4*>(&xs[buf][tid * 4]) = nxt;
        __syncthreads();
        int tnext = tile + gridDim.x;
        if (tid < 96 && tnext < ntiles)
            nxt = x4[(long long)tnext * 96 + tid];   // in flight during compute

        // ---- y = A@x for node-row r (24 fma) ----
        float xv[24];
        #pragma unroll
        for (int i = 0; i < 6; i++) {
            float4 v = *reinterpret_cast<float4*>(&xs[buf][g * 24 + i * 4]);
            xv[4 * i] = v.x; xv[4 * i + 1] = v.y; xv[4 * i + 2] = v.z; xv[4 * i + 3] = v.w;
        }
        float y0 = 0.f, y1 = 0.f, y2 = 0.f;
        #pragma unroll
        for (int m = 0; m < 8; m++) {
            y0 = fmaf(arow[m], xv[m * 3 + 0], y0);
            y1 = fmaf(arow[m], xv[m * 3 + 1], y1);
            y2 = fmaf(arow[m], xv[m * 3 + 2], y2);
        }

        // ---- shared accumulator for all three MFMA stages ----
        f32x16 vacc;

        // ---- layer 1 via 2 kappa-packed MFMAs (bias in slot 3) ----
        bf16x8 yB;
        #pragma unroll
        for (int j = 0; j < 8; j++) yB[j] = (__bf16)0.0f;
        {
            __bf16 h0 = (__bf16)y0, h1b = (__bf16)y1, h2b = (__bf16)y2;
            __bf16 l0 = (__bf16)(y0 - (float)h0);
            __bf16 l1 = (__bf16)(y1 - (float)h1b);
            __bf16 l2 = (__bf16)(y2 - (float)h2b);
            yB[0] = q ? l0 : h0; yB[1] = q ? l1 : h1b; yB[2] = q ? l2 : h2b;
            yB[3] = q ? (__bf16)0.0f : (__bf16)1.0f;
        }
        #pragma unroll
        for (int k = 0; k < 16; k++) vacc[k] = 0.0f;
        vacc = __builtin_amdgcn_mfma_f32_32x32x16_bf16(w1Ahi, yB, vacc, 0, 0, 0);
        vacc = __builtin_amdgcn_mfma_f32_32x32x16_bf16(w1Alo, yB, vacc, 0, 0, 0);

        // ---- relu -> h1 (lane=node, regs=hidden rr), hi-only A-frags ----
        bf16x8 phi[2];
        #pragma unroll
        for (int s = 0; s < 2; s++) {
            #pragma unroll
            for (int j = 0; j < 8; j++)
                phi[s][j] = (__bf16)fmaxf(vacc[8 * s + j], 0.0f);
        }

        // ---- GEMM1: t = bf16(h1) @ bf16(W2) (2 MFMA; pi both sides) ----
        #pragma unroll
        for (int k = 0; k < 16; k++) vacc[k] = 0.0f;
        vacc = __builtin_amdgcn_mfma_f32_32x32x16_bf16(phi[0], w2hi[0], vacc, 0, 0, 0);
        vacc = __builtin_amdgcn_mfma_f32_32x32x16_bf16(phi[1], w2hi[1], vacc, 0, 0, 0);

        // ---- tT A-frag: hi-only DIRECT conversion ----
        bf16x8 thi[2];
        #pragma unroll
        for (int s = 0; s < 2; s++) {
            #pragma unroll
            for (int j = 0; j < 8; j++)
                thi[s][j] = (__bf16)vacc[8 * s + j];
        }

        // ---- aggregation: h2T = tT @ A32T (2 MFMA; + b2 folded into init) ----
        #pragma unroll
        for (int k = 0; k < 16; k++) vacc[k] = b2r[k];
        vacc = __builtin_amdgcn_mfma_f32_32x32x16_bf16(thi[0], a32hi[0], vacc, 0, 0, 0);
        vacc = __builtin_amdgcn_mfma_f32_32x32x16_bf16(thi[1], a32hi[1], vacc, 0, 0, 0);

        // ---- epilogue: lane=node, regs=hidden -> in-register reduction ----
        float ssum = 0.0f;
        #pragma unroll
        for (int k = 0; k < 16; k++)
            ssum = fmaf(fmaxf(vacc[k], 0.0f), woutr[k], ssum);
        ssum += __shfl_xor(ssum, 32, 64);          // other hidden half
        float o = fmaxf(ssum + boutv, 0.0f);       // relu per node
        o += __shfl_xor(o, 1, 64);
        o += __shfl_xor(o, 2, 64);
        o += __shfl_xor(o, 4, 64);                 // sum 8 nodes of my graph
        if (q == 0 && n8 == 0) {
            long long gg = gbase + g;
            if (gg < (long long)B) out[gg] = o * 0.125f;
        }
        buf ^= 1;
    }
}

extern "C" void kernel_launch(void* const* d_in, const int* in_sizes, int n_in,
                              void* d_out, int out_size, void* d_ws, size_t ws_size,
                              hipStream_t stream) {
    const float* x    = (const float*)d_in[0];
    const int*   ei   = (const int*)d_in[1];
    const float* W1   = (const float*)d_in[2];
    const float* b1   = (const float*)d_in[3];
    const float* W2   = (const float*)d_in[4];
    const float* b2   = (const float*)d_in[5];
    const float* Wout = (const float*)d_in[6];
    const float* bout = (const float*)d_in[7];
    float* out = (float*)d_out;
    (void)d_ws; (void)ws_size; (void)out_size; (void)n_in;

    const int B = in_sizes[0] / 24;                 // 262144
    const int ntiles = (B + GPT - 1) / GPT;         // 16384
    const int grid = ntiles < 2048 ? ntiles : 2048; // grid-stride, 8 iters/block
    gnn_kernel<<<grid, 256, 0, stream>>>(x, ei, W1, b1, W2, b2, Wout, bout, out, B, ntiles);
}

// Round 18
// 57.854 us; speedup vs baseline: 1.0072x; 1.0072x over previous
//
#include <hip/hip_runtime.h>

// VanillaGNN via MFMA: B=262144 graphs, N=8 nodes, DIN=3, DH=32, DOUT=1.
// Round-16 base (35.2us) + coupled pair to claim the 128-reg bin:
//  (1) b2r/woutr (32 regs) -> LDS broadcast reads in epilogue (EXONERATED:
//      r12's 393K conflicts were LDS-SPILL ds-ops, not these reads; r17
//      proved it via LDS_Block_Size 16896 = 8704 + 8KB spill)
//  (2) __launch_bounds__(256,4): with the 32-reg diet the live set (~95)
//      now fits the 128 envelope without spill.
// CANARIES: LDS_Block_Size MUST stay 8704 (spill->LDS), FETCH ~12.3MB
// (spill->scratch), absmax exactly 1.2207e-4 (b2-add reassociation exact).
// Chain per wave (4 graphs = 32 node-rows):
//   y = A@x (24 fma) -> L1: P = W1split @ ysplit + b1 (2 kappa-packed MFMA,
//   relu) -> GEMM1: t = bf16(h1) @ bf16(W2) (2 MFMA; pi both sides) ->
//   AGG: h2T = bf16(tT) @ bf16(A32T) (2 MFMA) -> epilogue: +b2/relu/wout
//   from LDS (broadcast float4), in-register reduction + shfl tree.
// Precision ledger (all measured-free, absmax pinned at grid floor 1.2207e-4):
//   tlo (r12/13), w2lo+a32lo (r15), plo (r16).
// Verified layouts (gfx950 mfma_f32_32x32x16_bf16, rounds 3-16):
//   A: lane row=l&31, k=s*16+8*(l>>5)+j   B: col=l&31, same k
//   C/D: col=l&31, row=(reg&3)+8*(reg>>2)+4*(l>>5)
// pi(kk) = rr(kk) = (kk&3)+8*(kk>>2)+4q  (logical index of reg kk).

typedef __bf16 bf16x8 __attribute__((ext_vector_type(8)));
typedef float  f32x16 __attribute__((ext_vector_type(16)));

#define GPT 16  // graphs per block tile (4 waves x 4 graphs)

__global__ __launch_bounds__(256, 4) void gnn_kernel(
    const float* __restrict__ x,       // [B,8,3]
    const int* __restrict__ ei,        // [2,32] int32
    const float* __restrict__ W1,      // [3,32]
    const float* __restrict__ b1,      // [32]
    const float* __restrict__ W2,      // [32,32]
    const float* __restrict__ b2,      // [32]
    const float* __restrict__ Wout,    // [32]
    const float* __restrict__ bout,    // [1]
    float* __restrict__ out,           // [B]
    int B, int ntiles)
{
    __shared__ float As[64];           // A[n][m] (n=dst)
    __shared__ float degs[8], dinvs[8];
    __shared__ float W1s[96], b1s[32], W2s[1024], b2s[32], Wouts[32];
    __shared__ float xs[2][GPT * 24];  // double-buffered [g][8][3]

    const int tid = threadIdx.x;

    // ---- stage weights / build A (once per block) ----
    if (tid < 96) W1s[tid] = W1[tid];
    if (tid < 64) As[tid] = 0.0f;
    if (tid < 32) { b1s[tid] = b1[tid]; b2s[tid] = b2[tid]; Wouts[tid] = Wout[tid]; }
    if (tid < 8)  degs[tid] = 1.0f;
    for (int i = tid; i < 1024; i += 256) W2s[i] = W2[i];
    __syncthreads();
    if (tid < 32) { int d = ei[32 + tid]; atomicAdd(&degs[d], 1.0f); }
    __syncthreads();
    if (tid < 8) dinvs[tid] = 1.0f / sqrtf(degs[tid]);
    __syncthreads();
    if (tid < 32) {
        int s = ei[tid], d = ei[32 + tid];
        atomicAdd(&As[d * 8 + s], dinvs[s] * dinvs[d]);
    } else if (tid < 40) {
        int n = tid - 32;
        atomicAdd(&As[n * 8 + n], dinvs[n] * dinvs[n]);
    }
    __syncthreads();

    // ---- per-lane constants ----
    const int lane = tid & 63;
    const int wv   = tid >> 6;    // wave 0..3
    const int r    = lane & 31;
    const int q    = lane >> 5;   // k-half / row-half selector
    const int n8   = r & 7;       // node within graph
    const int gl   = r >> 3;      // graph within wave
    const int g    = wv * 4 + gl; // block-local graph

    float arow[8];
    #pragma unroll
    for (int m = 0; m < 8; m++) arow[m] = As[n8 * 8 + m];

    // W1^T A-frags, kappa-packed: slots 0-2 = W1[j][r] (hi step0 / lo step1),
    // slot 3 = b1[r] (hi step0 / lo step1; paired with B slot3 = q?0:1)
    bf16x8 w1Ahi, w1Alo;
    #pragma unroll
    for (int j = 0; j < 8; j++) { w1Ahi[j] = (__bf16)0.0f; w1Alo[j] = (__bf16)0.0f; }
    #pragma unroll
    for (int j = 0; j < 3; j++) {
        float v = W1s[j * 32 + r];
        __bf16 h = (__bf16)v;
        w1Ahi[j] = h; w1Alo[j] = (__bf16)(v - (float)h);
    }
    {
        float v = b1s[r];
        __bf16 h = (__bf16)v;
        w1Ahi[3] = h; w1Alo[3] = (__bf16)(v - (float)h);
    }

    // W2 B-frags in pi-order (hi only): slot (s,j), kk=8s+j ->
    //   hidden-in rr(kk) = (kk&3)+8*(kk>>2)+4q ; value bf16(W2[rr(kk)][r])
    bf16x8 w2hi[2];
    #pragma unroll
    for (int s = 0; s < 2; s++) {
        #pragma unroll
        for (int j = 0; j < 8; j++) {
            int kk = 8 * s + j;
            int hid = (kk & 3) + 8 * (kk >> 2) + 4 * q;
            w2hi[s][j] = (__bf16)W2s[hid * 32 + r];
        }
    }
    // A32T B-frags in pi-order (hi only): slot (s,j), kk=8s+j
    //   -> node (kk&3)+4q of graph kk>>2, gated to own graph
    bf16x8 a32hi[2];
    #pragma unroll
    for (int s = 0; s < 2; s++) {
        #pragma unroll
        for (int j = 0; j < 8; j++) {
            int kk = 8 * s + j;
            float v = ((kk >> 2) == gl) ? arow[(kk & 3) + 4 * q] : 0.0f;
            a32hi[s][j] = (__bf16)v;
        }
    }
    const float boutv = bout[0];

    // ---- x prefetch (tile 0) ----
    const float4* x4 = reinterpret_cast<const float4*>(x);
    float4 nxt;
    if (tid < 96 && blockIdx.x < ntiles)
        nxt = x4[(long long)blockIdx.x * 96 + tid];
    int buf = 0;

    // ---- tile loop: 1 barrier/tile; prefetch issued after the barrier ----
    for (int tile = blockIdx.x; tile < ntiles; tile += gridDim.x) {
        const long long gbase = (long long)tile * GPT;
        if (tid < 96) *reinterpret_cast<float4*>(&xs[buf][tid * 4]) = nxt;
        __syncthreads();
        int tnext = tile + gridDim.x;
        if (tid < 96 && tnext < ntiles)
            nxt = x4[(long long)tnext * 96 + tid];   // in flight during compute

        // ---- y = A@x for node-row r (24 fma) ----
        float xv[24];
        #pragma unroll
        for (int i = 0; i < 6; i++) {
            float4 v = *reinterpret_cast<float4*>(&xs[buf][g * 24 + i * 4]);
            xv[4 * i] = v.x; xv[4 * i + 1] = v.y; xv[4 * i + 2] = v.z; xv[4 * i + 3] = v.w;
        }
        float y0 = 0.f, y1 = 0.f, y2 = 0.f;
        #pragma unroll
        for (int m = 0; m < 8; m++) {
            y0 = fmaf(arow[m], xv[m * 3 + 0], y0);
            y1 = fmaf(arow[m], xv[m * 3 + 1], y1);
            y2 = fmaf(arow[m], xv[m * 3 + 2], y2);
        }

        // ---- shared accumulator for all three MFMA stages ----
        f32x16 vacc;

        // ---- layer 1 via 2 kappa-packed MFMAs (bias in slot 3) ----
        bf16x8 yB;
        #pragma unroll
        for (int j = 0; j < 8; j++) yB[j] = (__bf16)0.0f;
        {
            __bf16 h0 = (__bf16)y0, h1b = (__bf16)y1, h2b = (__bf16)y2;
            __bf16 l0 = (__bf16)(y0 - (float)h0);
            __bf16 l1 = (__bf16)(y1 - (float)h1b);
            __bf16 l2 = (__bf16)(y2 - (float)h2b);
            yB[0] = q ? l0 : h0; yB[1] = q ? l1 : h1b; yB[2] = q ? l2 : h2b;
            yB[3] = q ? (__bf16)0.0f : (__bf16)1.0f;
        }
        #pragma unroll
        for (int k = 0; k < 16; k++) vacc[k] = 0.0f;
        vacc = __builtin_amdgcn_mfma_f32_32x32x16_bf16(w1Ahi, yB, vacc, 0, 0, 0);
        vacc = __builtin_amdgcn_mfma_f32_32x32x16_bf16(w1Alo, yB, vacc, 0, 0, 0);

        // ---- relu -> h1 (lane=node, regs=hidden rr), hi-only A-frags ----
        bf16x8 phi[2];
        #pragma unroll
        for (int s = 0; s < 2; s++) {
            #pragma unroll
            for (int j = 0; j < 8; j++)
                phi[s][j] = (__bf16)fmaxf(vacc[8 * s + j], 0.0f);
        }

        // ---- GEMM1: t = bf16(h1) @ bf16(W2) (2 MFMA; pi both sides) ----
        #pragma unroll
        for (int k = 0; k < 16; k++) vacc[k] = 0.0f;
        vacc = __builtin_amdgcn_mfma_f32_32x32x16_bf16(phi[0], w2hi[0], vacc, 0, 0, 0);
        vacc = __builtin_amdgcn_mfma_f32_32x32x16_bf16(phi[1], w2hi[1], vacc, 0, 0, 0);

        // ---- tT A-frag: hi-only DIRECT conversion ----
        bf16x8 thi[2];
        #pragma unroll
        for (int s = 0; s < 2; s++) {
            #pragma unroll
            for (int j = 0; j < 8; j++)
                thi[s][j] = (__bf16)vacc[8 * s + j];
        }

        // ---- aggregation: h2T = tT @ A32T (2 MFMA; b2 added in epilogue) ----
        #pragma unroll
        for (int k = 0; k < 16; k++) vacc[k] = 0.0f;
        vacc = __builtin_amdgcn_mfma_f32_32x32x16_bf16(thi[0], a32hi[0], vacc, 0, 0, 0);
        vacc = __builtin_amdgcn_mfma_f32_32x32x16_bf16(thi[1], a32hi[1], vacc, 0, 0, 0);

        // ---- epilogue: +b2/relu/wout from LDS (broadcast float4: reg group
        //      gk holds hidden rows 8gk+4q..+3 -> contiguous, 2 addrs/wave) ----
        float ssum = 0.0f;
        #pragma unroll
        for (int gk = 0; gk < 4; gk++) {
            float4 vb = *reinterpret_cast<const float4*>(&b2s[8 * gk + 4 * q]);
            float4 vw = *reinterpret_cast<const float4*>(&Wouts[8 * gk + 4 * q]);
            ssum = fmaf(fmaxf(vacc[4 * gk + 0] + vb.x, 0.0f), vw.x, ssum);
            ssum = fmaf(fmaxf(vacc[4 * gk + 1] + vb.y, 0.0f), vw.y, ssum);
            ssum = fmaf(fmaxf(vacc[4 * gk + 2] + vb.z, 0.0f), vw.z, ssum);
            ssum = fmaf(fmaxf(vacc[4 * gk + 3] + vb.w, 0.0f), vw.w, ssum);
        }
        ssum += __shfl_xor(ssum, 32, 64);          // other hidden half
        float o = fmaxf(ssum + boutv, 0.0f);       // relu per node
        o += __shfl_xor(o, 1, 64);
        o += __shfl_xor(o, 2, 64);
        o += __shfl_xor(o, 4, 64);                 // sum 8 nodes of my graph
        if (q == 0 && n8 == 0) {
            long long gg = gbase + g;
            if (gg < (long long)B) out[gg] = o * 0.125f;
        }
        buf ^= 1;
    }
}

extern "C" void kernel_launch(void* const* d_in, const int* in_sizes, int n_in,
                              void* d_out, int out_size, void* d_ws, size_t ws_size,
                              hipStream_t stream) {
    const float* x    = (const float*)d_in[0];
    const int*   ei   = (const int*)d_in[1];
    const float* W1   = (const float*)d_in[2];
    const float* b1   = (const float*)d_in[3];
    const float* W2   = (const float*)d_in[4];
    const float* b2   = (const float*)d_in[5];
    const float* Wout = (const float*)d_in[6];
    const float* bout = (const float*)d_in[7];
    float* out = (float*)d_out;
    (void)d_ws; (void)ws_size; (void)out_size; (void)n_in;

    const int B = in_sizes[0] / 24;                 // 262144
    const int ntiles = (B + GPT - 1) / GPT;         // 16384
    const int grid = ntiles < 2048 ? ntiles : 2048; // grid-stride, 8 iters/block
    gnn_kernel<<<grid, 256, 0, stream>>>(x, ei, W1, b1, W2, b2, Wout, bout, out, B, ntiles);
}

// Round 19
// 37.646 us; speedup vs baseline: 1.5479x; 1.5368x over previous
//
#include <hip/hip_runtime.h>

// VanillaGNN via MFMA: B=262144 graphs, N=8 nodes, DIN=3, DH=32, DOUT=1.
// Round-16 source (35.2us, best) + ONE token: __launch_bounds__(256) with NO
// waves-per-EU arg. r17/r18 proved the 128 envelope is unfittable (LDS spill
// both times, even after a 32-reg diet). Hypothesis under test: the
// (256,2) attr itself makes the allocator claim the 256-reg envelope
// (descriptor in the 256-bin -> 2 waves/SIMD) even though live usage is
// ~88 regs. Removing the attr lets HW occupancy follow ACTUAL allocation.
// CANARIES: LDS_Block_Size 8704 (spill->LDS), FETCH ~12.3MB (spill->scratch),
// absmax exactly 1.2207e-4 (no semantic change).
// Chain per wave (4 graphs = 32 node-rows):
//   y = A@x (24 fma) -> L1: P = W1split @ ysplit + b1 (2 kappa-packed MFMA,
//   relu) -> GEMM1: t = bf16(h1) @ bf16(W2) (2 MFMA; pi both sides) ->
//   AGG: h2T = bf16(tT) @ bf16(A32T) (2 MFMA) -> in-register Wout reduction.
// Precision ledger (all measured-free, absmax pinned at grid floor 1.2207e-4):
//   tlo (r12/13), w2lo+a32lo (r15), plo (r16).
// Verified layouts (gfx950 mfma_f32_32x32x16_bf16, rounds 3-16):
//   A: lane row=l&31, k=s*16+8*(l>>5)+j   B: col=l&31, same k
//   C/D: col=l&31, row=(reg&3)+8*(reg>>2)+4*(l>>5)
// pi(kk) = rr(kk) = (kk&3)+8*(kk>>2)+4q  (logical index of reg kk).

typedef __bf16 bf16x8 __attribute__((ext_vector_type(8)));
typedef float  f32x16 __attribute__((ext_vector_type(16)));

#define GPT 16  // graphs per block tile (4 waves x 4 graphs)

__global__ __launch_bounds__(256) void gnn_kernel(
    const float* __restrict__ x,       // [B,8,3]
    const int* __restrict__ ei,        // [2,32] int32
    const float* __restrict__ W1,      // [3,32]
    const float* __restrict__ b1,      // [32]
    const float* __restrict__ W2,      // [32,32]
    const float* __restrict__ b2,      // [32]
    const float* __restrict__ Wout,    // [32]
    const float* __restrict__ bout,    // [1]
    float* __restrict__ out,           // [B]
    int B, int ntiles)
{
    __shared__ float As[64];           // A[n][m] (n=dst)
    __shared__ float degs[8], dinvs[8];
    __shared__ float W1s[96], b1s[32], W2s[1024], b2s[32], Wouts[32];
    __shared__ float xs[2][GPT * 24];  // double-buffered [g][8][3]

    const int tid = threadIdx.x;

    // ---- stage weights / build A (once per block) ----
    if (tid < 96) W1s[tid] = W1[tid];
    if (tid < 64) As[tid] = 0.0f;
    if (tid < 32) { b1s[tid] = b1[tid]; b2s[tid] = b2[tid]; Wouts[tid] = Wout[tid]; }
    if (tid < 8)  degs[tid] = 1.0f;
    for (int i = tid; i < 1024; i += 256) W2s[i] = W2[i];
    __syncthreads();
    if (tid < 32) { int d = ei[32 + tid]; atomicAdd(&degs[d], 1.0f); }
    __syncthreads();
    if (tid < 8) dinvs[tid] = 1.0f / sqrtf(degs[tid]);
    __syncthreads();
    if (tid < 32) {
        int s = ei[tid], d = ei[32 + tid];
        atomicAdd(&As[d * 8 + s], dinvs[s] * dinvs[d]);
    } else if (tid < 40) {
        int n = tid - 32;
        atomicAdd(&As[n * 8 + n], dinvs[n] * dinvs[n]);
    }
    __syncthreads();

    // ---- per-lane constants ----
    const int lane = tid & 63;
    const int wv   = tid >> 6;    // wave 0..3
    const int r    = lane & 31;
    const int q    = lane >> 5;   // k-half / row-half selector
    const int n8   = r & 7;       // node within graph
    const int gl   = r >> 3;      // graph within wave
    const int g    = wv * 4 + gl; // block-local graph

    float arow[8];
    #pragma unroll
    for (int m = 0; m < 8; m++) arow[m] = As[n8 * 8 + m];

    // W1^T A-frags, kappa-packed: slots 0-2 = W1[j][r] (hi step0 / lo step1),
    // slot 3 = b1[r] (hi step0 / lo step1; paired with B slot3 = q?0:1)
    bf16x8 w1Ahi, w1Alo;
    #pragma unroll
    for (int j = 0; j < 8; j++) { w1Ahi[j] = (__bf16)0.0f; w1Alo[j] = (__bf16)0.0f; }
    #pragma unroll
    for (int j = 0; j < 3; j++) {
        float v = W1s[j * 32 + r];
        __bf16 h = (__bf16)v;
        w1Ahi[j] = h; w1Alo[j] = (__bf16)(v - (float)h);
    }
    {
        float v = b1s[r];
        __bf16 h = (__bf16)v;
        w1Ahi[3] = h; w1Alo[3] = (__bf16)(v - (float)h);
    }

    // W2 B-frags in pi-order (hi only): slot (s,j), kk=8s+j ->
    //   hidden-in rr(kk) = (kk&3)+8*(kk>>2)+4q ; value bf16(W2[rr(kk)][r])
    bf16x8 w2hi[2];
    #pragma unroll
    for (int s = 0; s < 2; s++) {
        #pragma unroll
        for (int j = 0; j < 8; j++) {
            int kk = 8 * s + j;
            int hid = (kk & 3) + 8 * (kk >> 2) + 4 * q;
            w2hi[s][j] = (__bf16)W2s[hid * 32 + r];
        }
    }
    // A32T B-frags in pi-order (hi only): slot (s,j), kk=8s+j
    //   -> node (kk&3)+4q of graph kk>>2, gated to own graph
    bf16x8 a32hi[2];
    #pragma unroll
    for (int s = 0; s < 2; s++) {
        #pragma unroll
        for (int j = 0; j < 8; j++) {
            int kk = 8 * s + j;
            float v = ((kk >> 2) == gl) ? arow[(kk & 3) + 4 * q] : 0.0f;
            a32hi[s][j] = (__bf16)v;
        }
    }
    // epilogue per-reg constants: reg k holds hidden row hk = rr(k)
    float b2r[16], woutr[16];
    #pragma unroll
    for (int k = 0; k < 16; k++) {
        int hk = (k & 3) + 8 * (k >> 2) + 4 * q;
        b2r[k] = b2s[hk]; woutr[k] = Wouts[hk];
    }
    const float boutv = bout[0];

    // ---- x prefetch (tile 0) ----
    const float4* x4 = reinterpret_cast<const float4*>(x);
    float4 nxt;
    if (tid < 96 && blockIdx.x < ntiles)
        nxt = x4[(long long)blockIdx.x * 96 + tid];
    int buf = 0;

    // ---- tile loop: 1 barrier/tile; prefetch issued after the barrier ----
    for (int tile = blockIdx.x; tile < ntiles; tile += gridDim.x) {
        const long long gbase = (long long)tile * GPT;
        if (tid < 96) *reinterpret_cast<float4*>(&xs[buf][tid * 4]) = nxt;
        __syncthreads();
        int tnext = tile + gridDim.x;
        if (tid < 96 && tnext < ntiles)
            nxt = x4[(long long)tnext * 96 + tid];   // in flight during compute

        // ---- y = A@x for node-row r (24 fma) ----
        float xv[24];
        #pragma unroll
        for (int i = 0; i < 6; i++) {
            float4 v = *reinterpret_cast<float4*>(&xs[buf][g * 24 + i * 4]);
            xv[4 * i] = v.x; xv[4 * i + 1] = v.y; xv[4 * i + 2] = v.z; xv[4 * i + 3] = v.w;
        }
        float y0 = 0.f, y1 = 0.f, y2 = 0.f;
        #pragma unroll
        for (int m = 0; m < 8; m++) {
            y0 = fmaf(arow[m], xv[m * 3 + 0], y0);
            y1 = fmaf(arow[m], xv[m * 3 + 1], y1);
            y2 = fmaf(arow[m], xv[m * 3 + 2], y2);
        }

        // ---- shared accumulator for all three MFMA stages ----
        f32x16 vacc;

        // ---- layer 1 via 2 kappa-packed MFMAs (bias in slot 3) ----
        bf16x8 yB;
        #pragma unroll
        for (int j = 0; j < 8; j++) yB[j] = (__bf16)0.0f;
        {
            __bf16 h0 = (__bf16)y0, h1b = (__bf16)y1, h2b = (__bf16)y2;
            __bf16 l0 = (__bf16)(y0 - (float)h0);
            __bf16 l1 = (__bf16)(y1 - (float)h1b);
            __bf16 l2 = (__bf16)(y2 - (float)h2b);
            yB[0] = q ? l0 : h0; yB[1] = q ? l1 : h1b; yB[2] = q ? l2 : h2b;
            yB[3] = q ? (__bf16)0.0f : (__bf16)1.0f;
        }
        #pragma unroll
        for (int k = 0; k < 16; k++) vacc[k] = 0.0f;
        vacc = __builtin_amdgcn_mfma_f32_32x32x16_bf16(w1Ahi, yB, vacc, 0, 0, 0);
        vacc = __builtin_amdgcn_mfma_f32_32x32x16_bf16(w1Alo, yB, vacc, 0, 0, 0);

        // ---- relu -> h1 (lane=node, regs=hidden rr), hi-only A-frags ----
        bf16x8 phi[2];
        #pragma unroll
        for (int s = 0; s < 2; s++) {
            #pragma unroll
            for (int j = 0; j < 8; j++)
                phi[s][j] = (__bf16)fmaxf(vacc[8 * s + j], 0.0f);
        }

        // ---- GEMM1: t = bf16(h1) @ bf16(W2) (2 MFMA; pi both sides) ----
        #pragma unroll
        for (int k = 0; k < 16; k++) vacc[k] = 0.0f;
        vacc = __builtin_amdgcn_mfma_f32_32x32x16_bf16(phi[0], w2hi[0], vacc, 0, 0, 0);
        vacc = __builtin_amdgcn_mfma_f32_32x32x16_bf16(phi[1], w2hi[1], vacc, 0, 0, 0);

        // ---- tT A-frag: hi-only DIRECT conversion ----
        bf16x8 thi[2];
        #pragma unroll
        for (int s = 0; s < 2; s++) {
            #pragma unroll
            for (int j = 0; j < 8; j++)
                thi[s][j] = (__bf16)vacc[8 * s + j];
        }

        // ---- aggregation: h2T = tT @ A32T (2 MFMA; + b2 folded into init) ----
        #pragma unroll
        for (int k = 0; k < 16; k++) vacc[k] = b2r[k];
        vacc = __builtin_amdgcn_mfma_f32_32x32x16_bf16(thi[0], a32hi[0], vacc, 0, 0, 0);
        vacc = __builtin_amdgcn_mfma_f32_32x32x16_bf16(thi[1], a32hi[1], vacc, 0, 0, 0);

        // ---- epilogue: lane=node, regs=hidden -> in-register reduction ----
        float ssum = 0.0f;
        #pragma unroll
        for (int k = 0; k < 16; k++)
            ssum = fmaf(fmaxf(vacc[k], 0.0f), woutr[k], ssum);
        ssum += __shfl_xor(ssum, 32, 64);          // other hidden half
        float o = fmaxf(ssum + boutv, 0.0f);       // relu per node
        o += __shfl_xor(o, 1, 64);
        o += __shfl_xor(o, 2, 64);
        o += __shfl_xor(o, 4, 64);                 // sum 8 nodes of my graph
        if (q == 0 && n8 == 0) {
            long long gg = gbase + g;
            if (gg < (long long)B) out[gg] = o * 0.125f;
        }
        buf ^= 1;
    }
}

extern "C" void kernel_launch(void* const* d_in, const int* in_sizes, int n_in,
                              void* d_out, int out_size, void* d_ws, size_t ws_size,
                              hipStream_t stream) {
    const float* x    = (const float*)d_in[0];
    const int*   ei   = (const int*)d_in[1];
    const float* W1   = (const float*)d_in[2];
    const float* b1   = (const float*)d_in[3];
    const float* W2   = (const float*)d_in[4];
    const float* b2   = (const float*)d_in[5];
    const float* Wout = (const float*)d_in[6];
    const float* bout = (const float*)d_in[7];
    float* out = (float*)d_out;
    (void)d_ws; (void)ws_size; (void)out_size; (void)n_in;

    const int B = in_sizes[0] / 24;                 // 262144
    const int ntiles = (B + GPT - 1) / GPT;         // 16384
    const int grid = ntiles < 2048 ? ntiles : 2048; // grid-stride, 8 iters/block
    gnn_kernel<<<grid, 256, 0, stream>>>(x, ei, W1, b1, W2, b2, Wout, bout, out, B, ntiles);
}

// Round 20
// 32.340 us; speedup vs baseline: 1.8019x; 1.1641x over previous
//
#include <hip/hip_runtime.h>

// VanillaGNN via MFMA: B=262144 graphs, N=8 nodes, DIN=3, DH=32, DOUT=1.
// Round-16 math (35.2us) + manual ILP-2: each wave runs TWO pipelines
// (graphs g and g+16; GPT=32) with every MFMA issued in alternating p0/p1
// order — independent chains hide each other's MFMA latency. r6's ILP2
// failed because sequential lambda calls gave no interleave; this is
// straight-line, stage-interleaved, named variables (rule #20).
// Occupancy verdict (r13-r19): pinned at 2 waves/SIMD regardless of bounds;
// 129-256 bin is free real estate -> spend registers on ILP.
// CANARIES: absmax exactly 1.2207e-4; LDS ~11.5-12.5KB (+8KB = spill ->
// revert); FETCH ~12.3MB.
// Per pipeline: y = A@x (24 fma) -> L1: 2 kappa-packed MFMA (b1 in slot 3)
// -> relu/cvt -> GEMM1: 2 MFMA -> cvt -> AGG: 2 MFMA (b2 in acc init) ->
// Wout reduce + shfl tree.
// Verified layouts (gfx950 mfma_f32_32x32x16_bf16, rounds 3-16):
//   A: lane row=l&31, k=s*16+8*(l>>5)+j   B: col=l&31, same k
//   C/D: col=l&31, row=(reg&3)+8*(reg>>2)+4*(l>>5)
// pi(kk) = rr(kk) = (kk&3)+8*(kk>>2)+4q.
// Precision ledger (all measured-free): tlo, w2lo, a32lo, plo.

typedef __bf16 bf16x8 __attribute__((ext_vector_type(8)));
typedef float  f32x16 __attribute__((ext_vector_type(16)));

#define GPT 32  // graphs per block tile (4 waves x 2 pipelines x 4 graphs)

__global__ __launch_bounds__(256, 2) void gnn_kernel(
    const float* __restrict__ x,       // [B,8,3]
    const int* __restrict__ ei,        // [2,32] int32
    const float* __restrict__ W1,      // [3,32]
    const float* __restrict__ b1,      // [32]
    const float* __restrict__ W2,      // [32,32]
    const float* __restrict__ b2,      // [32]
    const float* __restrict__ Wout,    // [32]
    const float* __restrict__ bout,    // [1]
    float* __restrict__ out,           // [B]
    int B, int ntiles)
{
    __shared__ float As[64];           // A[n][m] (n=dst)
    __shared__ float degs[8], dinvs[8];
    __shared__ float W1s[96], b1s[32], W2s[1024], b2s[32], Wouts[32];
    __shared__ float xs[2][GPT * 24];  // double-buffered [g][8][3]

    const int tid = threadIdx.x;

    // ---- stage weights / build A (once per block) ----
    if (tid < 96) W1s[tid] = W1[tid];
    if (tid < 64) As[tid] = 0.0f;
    if (tid < 32) { b1s[tid] = b1[tid]; b2s[tid] = b2[tid]; Wouts[tid] = Wout[tid]; }
    if (tid < 8)  degs[tid] = 1.0f;
    for (int i = tid; i < 1024; i += 256) W2s[i] = W2[i];
    __syncthreads();
    if (tid < 32) { int d = ei[32 + tid]; atomicAdd(&degs[d], 1.0f); }
    __syncthreads();
    if (tid < 8) dinvs[tid] = 1.0f / sqrtf(degs[tid]);
    __syncthreads();
    if (tid < 32) {
        int s = ei[tid], d = ei[32 + tid];
        atomicAdd(&As[d * 8 + s], dinvs[s] * dinvs[d]);
    } else if (tid < 40) {
        int n = tid - 32;
        atomicAdd(&As[n * 8 + n], dinvs[n] * dinvs[n]);
    }
    __syncthreads();

    // ---- per-lane constants ----
    const int lane = tid & 63;
    const int wv   = tid >> 6;    // wave 0..3
    const int r    = lane & 31;
    const int q    = lane >> 5;   // k-half / row-half selector
    const int n8   = r & 7;       // node within graph
    const int gl   = r >> 3;      // graph within pipeline
    const int g0   = wv * 4 + gl;       // pipeline-0 graph
    const int g1   = 16 + wv * 4 + gl;  // pipeline-1 graph

    float arow[8];
    #pragma unroll
    for (int m = 0; m < 8; m++) arow[m] = As[n8 * 8 + m];

    // W1^T A-frags, kappa-packed: slots 0-2 = W1[j][r] (hi s0 / lo s1),
    // slot 3 = b1[r] (paired with B slot3 = q?0:1)
    bf16x8 w1Ahi, w1Alo;
    #pragma unroll
    for (int j = 0; j < 8; j++) { w1Ahi[j] = (__bf16)0.0f; w1Alo[j] = (__bf16)0.0f; }
    #pragma unroll
    for (int j = 0; j < 3; j++) {
        float v = W1s[j * 32 + r];
        __bf16 h = (__bf16)v;
        w1Ahi[j] = h; w1Alo[j] = (__bf16)(v - (float)h);
    }
    {
        float v = b1s[r];
        __bf16 h = (__bf16)v;
        w1Ahi[3] = h; w1Alo[3] = (__bf16)(v - (float)h);
    }

    // W2 B-frags in pi-order (hi only)
    bf16x8 w2hi[2];
    #pragma unroll
    for (int s = 0; s < 2; s++) {
        #pragma unroll
        for (int j = 0; j < 8; j++) {
            int kk = 8 * s + j;
            int hid = (kk & 3) + 8 * (kk >> 2) + 4 * q;
            w2hi[s][j] = (__bf16)W2s[hid * 32 + r];
        }
    }
    // A32T B-frags in pi-order (hi only)
    bf16x8 a32hi[2];
    #pragma unroll
    for (int s = 0; s < 2; s++) {
        #pragma unroll
        for (int j = 0; j < 8; j++) {
            int kk = 8 * s + j;
            float v = ((kk >> 2) == gl) ? arow[(kk & 3) + 4 * q] : 0.0f;
            a32hi[s][j] = (__bf16)v;
        }
    }
    // epilogue per-reg constants
    float b2r[16], woutr[16];
    #pragma unroll
    for (int k = 0; k < 16; k++) {
        int hk = (k & 3) + 8 * (k >> 2) + 4 * q;
        b2r[k] = b2s[hk]; woutr[k] = Wouts[hk];
    }
    const float boutv = bout[0];

    // ---- x prefetch (tile 0) ----
    const float4* x4 = reinterpret_cast<const float4*>(x);
    float4 nxt;
    if (tid < 192 && blockIdx.x < ntiles)
        nxt = x4[(long long)blockIdx.x * 192 + tid];
    int buf = 0;

    // ---- tile loop: 1 barrier per 2 pipelines; prefetch after barrier ----
    for (int tile = blockIdx.x; tile < ntiles; tile += gridDim.x) {
        const long long gbase = (long long)tile * GPT;
        if (tid < 192) *reinterpret_cast<float4*>(&xs[buf][tid * 4]) = nxt;
        __syncthreads();
        int tnext = tile + gridDim.x;
        if (tid < 192 && tnext < ntiles)
            nxt = x4[(long long)tnext * 192 + tid];   // in flight during compute

        // ---- y = A@x, pipeline 0 (shared xv scratch, reused for p1) ----
        float y00 = 0.f, y01 = 0.f, y02 = 0.f;
        {
            float xv[24];
            #pragma unroll
            for (int i = 0; i < 6; i++) {
                float4 v = *reinterpret_cast<float4*>(&xs[buf][g0 * 24 + i * 4]);
                xv[4 * i] = v.x; xv[4 * i + 1] = v.y; xv[4 * i + 2] = v.z; xv[4 * i + 3] = v.w;
            }
            #pragma unroll
            for (int m = 0; m < 8; m++) {
                y00 = fmaf(arow[m], xv[m * 3 + 0], y00);
                y01 = fmaf(arow[m], xv[m * 3 + 1], y01);
                y02 = fmaf(arow[m], xv[m * 3 + 2], y02);
            }
        }
        // ---- y = A@x, pipeline 1 ----
        float y10 = 0.f, y11 = 0.f, y12 = 0.f;
        {
            float xv[24];
            #pragma unroll
            for (int i = 0; i < 6; i++) {
                float4 v = *reinterpret_cast<float4*>(&xs[buf][g1 * 24 + i * 4]);
                xv[4 * i] = v.x; xv[4 * i + 1] = v.y; xv[4 * i + 2] = v.z; xv[4 * i + 3] = v.w;
            }
            #pragma unroll
            for (int m = 0; m < 8; m++) {
                y10 = fmaf(arow[m], xv[m * 3 + 0], y10);
                y11 = fmaf(arow[m], xv[m * 3 + 1], y11);
                y12 = fmaf(arow[m], xv[m * 3 + 2], y12);
            }
        }

        // ---- yB for both pipelines ----
        bf16x8 yB0, yB1;
        #pragma unroll
        for (int j = 0; j < 8; j++) { yB0[j] = (__bf16)0.0f; yB1[j] = (__bf16)0.0f; }
        {
            __bf16 h0 = (__bf16)y00, h1 = (__bf16)y01, h2 = (__bf16)y02;
            yB0[0] = q ? (__bf16)(y00 - (float)h0) : h0;
            yB0[1] = q ? (__bf16)(y01 - (float)h1) : h1;
            yB0[2] = q ? (__bf16)(y02 - (float)h2) : h2;
            yB0[3] = q ? (__bf16)0.0f : (__bf16)1.0f;
            __bf16 g0h = (__bf16)y10, g1h = (__bf16)y11, g2h = (__bf16)y12;
            yB1[0] = q ? (__bf16)(y10 - (float)g0h) : g0h;
            yB1[1] = q ? (__bf16)(y11 - (float)g1h) : g1h;
            yB1[2] = q ? (__bf16)(y12 - (float)g2h) : g2h;
            yB1[3] = q ? (__bf16)0.0f : (__bf16)1.0f;
        }

        // ---- L1 MFMAs, interleaved p0/p1 ----
        f32x16 vacc0, vacc1;
        #pragma unroll
        for (int k = 0; k < 16; k++) { vacc0[k] = 0.0f; vacc1[k] = 0.0f; }
        vacc0 = __builtin_amdgcn_mfma_f32_32x32x16_bf16(w1Ahi, yB0, vacc0, 0, 0, 0);
        vacc1 = __builtin_amdgcn_mfma_f32_32x32x16_bf16(w1Ahi, yB1, vacc1, 0, 0, 0);
        vacc0 = __builtin_amdgcn_mfma_f32_32x32x16_bf16(w1Alo, yB0, vacc0, 0, 0, 0);
        vacc1 = __builtin_amdgcn_mfma_f32_32x32x16_bf16(w1Alo, yB1, vacc1, 0, 0, 0);

        // ---- relu -> h1, hi-only A-frags, both pipelines ----
        bf16x8 phi0[2], phi1[2];
        #pragma unroll
        for (int s = 0; s < 2; s++) {
            #pragma unroll
            for (int j = 0; j < 8; j++) {
                phi0[s][j] = (__bf16)fmaxf(vacc0[8 * s + j], 0.0f);
                phi1[s][j] = (__bf16)fmaxf(vacc1[8 * s + j], 0.0f);
            }
        }

        // ---- GEMM1 MFMAs, interleaved ----
        #pragma unroll
        for (int k = 0; k < 16; k++) { vacc0[k] = 0.0f; vacc1[k] = 0.0f; }
        vacc0 = __builtin_amdgcn_mfma_f32_32x32x16_bf16(phi0[0], w2hi[0], vacc0, 0, 0, 0);
        vacc1 = __builtin_amdgcn_mfma_f32_32x32x16_bf16(phi1[0], w2hi[0], vacc1, 0, 0, 0);
        vacc0 = __builtin_amdgcn_mfma_f32_32x32x16_bf16(phi0[1], w2hi[1], vacc0, 0, 0, 0);
        vacc1 = __builtin_amdgcn_mfma_f32_32x32x16_bf16(phi1[1], w2hi[1], vacc1, 0, 0, 0);

        // ---- tT A-frags: hi-only DIRECT conversion, both ----
        bf16x8 thi0[2], thi1[2];
        #pragma unroll
        for (int s = 0; s < 2; s++) {
            #pragma unroll
            for (int j = 0; j < 8; j++) {
                thi0[s][j] = (__bf16)vacc0[8 * s + j];
                thi1[s][j] = (__bf16)vacc1[8 * s + j];
            }
        }

        // ---- AGG MFMAs, interleaved (b2 folded into init) ----
        #pragma unroll
        for (int k = 0; k < 16; k++) { vacc0[k] = b2r[k]; vacc1[k] = b2r[k]; }
        vacc0 = __builtin_amdgcn_mfma_f32_32x32x16_bf16(thi0[0], a32hi[0], vacc0, 0, 0, 0);
        vacc1 = __builtin_amdgcn_mfma_f32_32x32x16_bf16(thi1[0], a32hi[0], vacc1, 0, 0, 0);
        vacc0 = __builtin_amdgcn_mfma_f32_32x32x16_bf16(thi0[1], a32hi[1], vacc0, 0, 0, 0);
        vacc1 = __builtin_amdgcn_mfma_f32_32x32x16_bf16(thi1[1], a32hi[1], vacc1, 0, 0, 0);

        // ---- epilogues, interleaved (independent shfl chains) ----
        float ss0 = 0.0f, ss1 = 0.0f;
        #pragma unroll
        for (int k = 0; k < 16; k++) {
            ss0 = fmaf(fmaxf(vacc0[k], 0.0f), woutr[k], ss0);
            ss1 = fmaf(fmaxf(vacc1[k], 0.0f), woutr[k], ss1);
        }
        ss0 += __shfl_xor(ss0, 32, 64);
        ss1 += __shfl_xor(ss1, 32, 64);
        float o0 = fmaxf(ss0 + boutv, 0.0f);
        float o1 = fmaxf(ss1 + boutv, 0.0f);
        o0 += __shfl_xor(o0, 1, 64);  o1 += __shfl_xor(o1, 1, 64);
        o0 += __shfl_xor(o0, 2, 64);  o1 += __shfl_xor(o1, 2, 64);
        o0 += __shfl_xor(o0, 4, 64);  o1 += __shfl_xor(o1, 4, 64);
        if (q == 0 && n8 == 0) {
            long long gg0 = gbase + g0;
            if (gg0 < (long long)B) out[gg0] = o0 * 0.125f;
            long long gg1 = gbase + g1;
            if (gg1 < (long long)B) out[gg1] = o1 * 0.125f;
        }
        buf ^= 1;
    }
}

extern "C" void kernel_launch(void* const* d_in, const int* in_sizes, int n_in,
                              void* d_out, int out_size, void* d_ws, size_t ws_size,
                              hipStream_t stream) {
    const float* x    = (const float*)d_in[0];
    const int*   ei   = (const int*)d_in[1];
    const float* W1   = (const float*)d_in[2];
    const float* b1   = (const float*)d_in[3];
    const float* W2   = (const float*)d_in[4];
    const float* b2   = (const float*)d_in[5];
    const float* Wout = (const float*)d_in[6];
    const float* bout = (const float*)d_in[7];
    float* out = (float*)d_out;
    (void)d_ws; (void)ws_size; (void)out_size; (void)n_in;

    const int B = in_sizes[0] / 24;                 // 262144
    const int ntiles = (B + GPT - 1) / GPT;         // 8192
    const int grid = ntiles < 2048 ? ntiles : 2048; // grid-stride, 4 iters/block
    gnn_kernel<<<grid, 256, 0, stream>>>(x, ei, W1, b1, W2, b2, Wout, bout, out, B, ntiles);
}

// Round 21
// 32.339 us; speedup vs baseline: 1.8019x; 1.0000x over previous
//
#include <hip/hip_runtime.h>

// VanillaGNN via MFMA: B=262144 graphs, N=8 nodes, DIN=3, DH=32, DOUT=1.
// Round-20 base (32.3us, ILP2) + ONE change: MFMA C-operand init.
// The 96 per-tile acc-init v_movs (vacc=0 x2 stages x2 pipes, vacc=b2r x2)
// are deleted by passing persistent zerov / b2rv registers as the C operand
// of each stage's FIRST MFMA (D and C are separate fields in v_mfma).
// Bit-identical math; +32 persistent VGPR (free in the pinned 129-256 bin).
// CANARIES: absmax exactly 1.2207e-4; LDS 11776 (+8KB = spill -> revert);
// FETCH ~12.3MB.
// Per pipeline: y = A@x (24 fma) -> L1: 2 kappa-packed MFMA (b1 in slot 3,
// C=zerov) -> relu/cvt -> GEMM1: 2 MFMA (C=zerov) -> cvt -> AGG: 2 MFMA
// (C=b2rv) -> Wout reduce + shfl tree. All MFMAs issued p0/p1 alternating.
// Verified layouts (gfx950 mfma_f32_32x32x16_bf16, rounds 3-20):
//   A: lane row=l&31, k=s*16+8*(l>>5)+j   B: col=l&31, same k
//   C/D: col=l&31, row=(reg&3)+8*(reg>>2)+4*(l>>5)
// pi(kk) = rr(kk) = (kk&3)+8*(kk>>2)+4q.
// Precision ledger (all measured-free): tlo, w2lo, a32lo, plo.
// Occupancy verdict (r13-r19): pinned at 2 waves/SIMD; don't fight it.

typedef __bf16 bf16x8 __attribute__((ext_vector_type(8)));
typedef float  f32x16 __attribute__((ext_vector_type(16)));

#define GPT 32  // graphs per block tile (4 waves x 2 pipelines x 4 graphs)

__global__ __launch_bounds__(256, 2) void gnn_kernel(
    const float* __restrict__ x,       // [B,8,3]
    const int* __restrict__ ei,        // [2,32] int32
    const float* __restrict__ W1,      // [3,32]
    const float* __restrict__ b1,      // [32]
    const float* __restrict__ W2,      // [32,32]
    const float* __restrict__ b2,      // [32]
    const float* __restrict__ Wout,    // [32]
    const float* __restrict__ bout,    // [1]
    float* __restrict__ out,           // [B]
    int B, int ntiles)
{
    __shared__ float As[64];           // A[n][m] (n=dst)
    __shared__ float degs[8], dinvs[8];
    __shared__ float W1s[96], b1s[32], W2s[1024], b2s[32], Wouts[32];
    __shared__ float xs[2][GPT * 24];  // double-buffered [g][8][3]

    const int tid = threadIdx.x;

    // ---- stage weights / build A (once per block) ----
    if (tid < 96) W1s[tid] = W1[tid];
    if (tid < 64) As[tid] = 0.0f;
    if (tid < 32) { b1s[tid] = b1[tid]; b2s[tid] = b2[tid]; Wouts[tid] = Wout[tid]; }
    if (tid < 8)  degs[tid] = 1.0f;
    for (int i = tid; i < 1024; i += 256) W2s[i] = W2[i];
    __syncthreads();
    if (tid < 32) { int d = ei[32 + tid]; atomicAdd(&degs[d], 1.0f); }
    __syncthreads();
    if (tid < 8) dinvs[tid] = 1.0f / sqrtf(degs[tid]);
    __syncthreads();
    if (tid < 32) {
        int s = ei[tid], d = ei[32 + tid];
        atomicAdd(&As[d * 8 + s], dinvs[s] * dinvs[d]);
    } else if (tid < 40) {
        int n = tid - 32;
        atomicAdd(&As[n * 8 + n], dinvs[n] * dinvs[n]);
    }
    __syncthreads();

    // ---- per-lane constants ----
    const int lane = tid & 63;
    const int wv   = tid >> 6;    // wave 0..3
    const int r    = lane & 31;
    const int q    = lane >> 5;   // k-half / row-half selector
    const int n8   = r & 7;       // node within graph
    const int gl   = r >> 3;      // graph within pipeline
    const int g0   = wv * 4 + gl;       // pipeline-0 graph
    const int g1   = 16 + wv * 4 + gl;  // pipeline-1 graph

    float arow[8];
    #pragma unroll
    for (int m = 0; m < 8; m++) arow[m] = As[n8 * 8 + m];

    // W1^T A-frags, kappa-packed: slots 0-2 = W1[j][r] (hi s0 / lo s1),
    // slot 3 = b1[r] (paired with B slot3 = q?0:1)
    bf16x8 w1Ahi, w1Alo;
    #pragma unroll
    for (int j = 0; j < 8; j++) { w1Ahi[j] = (__bf16)0.0f; w1Alo[j] = (__bf16)0.0f; }
    #pragma unroll
    for (int j = 0; j < 3; j++) {
        float v = W1s[j * 32 + r];
        __bf16 h = (__bf16)v;
        w1Ahi[j] = h; w1Alo[j] = (__bf16)(v - (float)h);
    }
    {
        float v = b1s[r];
        __bf16 h = (__bf16)v;
        w1Ahi[3] = h; w1Alo[3] = (__bf16)(v - (float)h);
    }

    // W2 B-frags in pi-order (hi only)
    bf16x8 w2hi[2];
    #pragma unroll
    for (int s = 0; s < 2; s++) {
        #pragma unroll
        for (int j = 0; j < 8; j++) {
            int kk = 8 * s + j;
            int hid = (kk & 3) + 8 * (kk >> 2) + 4 * q;
            w2hi[s][j] = (__bf16)W2s[hid * 32 + r];
        }
    }
    // A32T B-frags in pi-order (hi only)
    bf16x8 a32hi[2];
    #pragma unroll
    for (int s = 0; s < 2; s++) {
        #pragma unroll
        for (int j = 0; j < 8; j++) {
            int kk = 8 * s + j;
            float v = ((kk >> 2) == gl) ? arow[(kk & 3) + 4 * q] : 0.0f;
            a32hi[s][j] = (__bf16)v;
        }
    }
    // persistent C-operand vectors: zero and b2 (pi-order); epilogue wout
    f32x16 zerov, b2rv;
    float woutr[16];
    #pragma unroll
    for (int k = 0; k < 16; k++) {
        int hk = (k & 3) + 8 * (k >> 2) + 4 * q;
        zerov[k] = 0.0f;
        b2rv[k] = b2s[hk];
        woutr[k] = Wouts[hk];
    }
    const float boutv = bout[0];

    // ---- x prefetch (tile 0) ----
    const float4* x4 = reinterpret_cast<const float4*>(x);
    float4 nxt;
    if (tid < 192 && blockIdx.x < ntiles)
        nxt = x4[(long long)blockIdx.x * 192 + tid];
    int buf = 0;

    // ---- tile loop: 1 barrier per 2 pipelines; prefetch after barrier ----
    for (int tile = blockIdx.x; tile < ntiles; tile += gridDim.x) {
        const long long gbase = (long long)tile * GPT;
        if (tid < 192) *reinterpret_cast<float4*>(&xs[buf][tid * 4]) = nxt;
        __syncthreads();
        int tnext = tile + gridDim.x;
        if (tid < 192 && tnext < ntiles)
            nxt = x4[(long long)tnext * 192 + tid];   // in flight during compute

        // ---- y = A@x, pipeline 0 ----
        float y00 = 0.f, y01 = 0.f, y02 = 0.f;
        {
            float xv[24];
            #pragma unroll
            for (int i = 0; i < 6; i++) {
                float4 v = *reinterpret_cast<float4*>(&xs[buf][g0 * 24 + i * 4]);
                xv[4 * i] = v.x; xv[4 * i + 1] = v.y; xv[4 * i + 2] = v.z; xv[4 * i + 3] = v.w;
            }
            #pragma unroll
            for (int m = 0; m < 8; m++) {
                y00 = fmaf(arow[m], xv[m * 3 + 0], y00);
                y01 = fmaf(arow[m], xv[m * 3 + 1], y01);
                y02 = fmaf(arow[m], xv[m * 3 + 2], y02);
            }
        }
        // ---- y = A@x, pipeline 1 ----
        float y10 = 0.f, y11 = 0.f, y12 = 0.f;
        {
            float xv[24];
            #pragma unroll
            for (int i = 0; i < 6; i++) {
                float4 v = *reinterpret_cast<float4*>(&xs[buf][g1 * 24 + i * 4]);
                xv[4 * i] = v.x; xv[4 * i + 1] = v.y; xv[4 * i + 2] = v.z; xv[4 * i + 3] = v.w;
            }
            #pragma unroll
            for (int m = 0; m < 8; m++) {
                y10 = fmaf(arow[m], xv[m * 3 + 0], y10);
                y11 = fmaf(arow[m], xv[m * 3 + 1], y11);
                y12 = fmaf(arow[m], xv[m * 3 + 2], y12);
            }
        }

        // ---- yB for both pipelines ----
        bf16x8 yB0, yB1;
        #pragma unroll
        for (int j = 0; j < 8; j++) { yB0[j] = (__bf16)0.0f; yB1[j] = (__bf16)0.0f; }
        {
            __bf16 h0 = (__bf16)y00, h1 = (__bf16)y01, h2 = (__bf16)y02;
            yB0[0] = q ? (__bf16)(y00 - (float)h0) : h0;
            yB0[1] = q ? (__bf16)(y01 - (float)h1) : h1;
            yB0[2] = q ? (__bf16)(y02 - (float)h2) : h2;
            yB0[3] = q ? (__bf16)0.0f : (__bf16)1.0f;
            __bf16 g0h = (__bf16)y10, g1h = (__bf16)y11, g2h = (__bf16)y12;
            yB1[0] = q ? (__bf16)(y10 - (float)g0h) : g0h;
            yB1[1] = q ? (__bf16)(y11 - (float)g1h) : g1h;
            yB1[2] = q ? (__bf16)(y12 - (float)g2h) : g2h;
            yB1[3] = q ? (__bf16)0.0f : (__bf16)1.0f;
        }

        // ---- L1 MFMAs, interleaved p0/p1; C = zerov (no init movs) ----
        f32x16 vacc0, vacc1;
        vacc0 = __builtin_amdgcn_mfma_f32_32x32x16_bf16(w1Ahi, yB0, zerov, 0, 0, 0);
        vacc1 = __builtin_amdgcn_mfma_f32_32x32x16_bf16(w1Ahi, yB1, zerov, 0, 0, 0);
        vacc0 = __builtin_amdgcn_mfma_f32_32x32x16_bf16(w1Alo, yB0, vacc0, 0, 0, 0);
        vacc1 = __builtin_amdgcn_mfma_f32_32x32x16_bf16(w1Alo, yB1, vacc1, 0, 0, 0);

        // ---- relu -> h1, hi-only A-frags, both pipelines ----
        bf16x8 phi0[2], phi1[2];
        #pragma unroll
        for (int s = 0; s < 2; s++) {
            #pragma unroll
            for (int j = 0; j < 8; j++) {
                phi0[s][j] = (__bf16)fmaxf(vacc0[8 * s + j], 0.0f);
                phi1[s][j] = (__bf16)fmaxf(vacc1[8 * s + j], 0.0f);
            }
        }

        // ---- GEMM1 MFMAs, interleaved; C = zerov ----
        vacc0 = __builtin_amdgcn_mfma_f32_32x32x16_bf16(phi0[0], w2hi[0], zerov, 0, 0, 0);
        vacc1 = __builtin_amdgcn_mfma_f32_32x32x16_bf16(phi1[0], w2hi[0], zerov, 0, 0, 0);
        vacc0 = __builtin_amdgcn_mfma_f32_32x32x16_bf16(phi0[1], w2hi[1], vacc0, 0, 0, 0);
        vacc1 = __builtin_amdgcn_mfma_f32_32x32x16_bf16(phi1[1], w2hi[1], vacc1, 0, 0, 0);

        // ---- tT A-frags: hi-only DIRECT conversion, both ----
        bf16x8 thi0[2], thi1[2];
        #pragma unroll
        for (int s = 0; s < 2; s++) {
            #pragma unroll
            for (int j = 0; j < 8; j++) {
                thi0[s][j] = (__bf16)vacc0[8 * s + j];
                thi1[s][j] = (__bf16)vacc1[8 * s + j];
            }
        }

        // ---- AGG MFMAs, interleaved; C = b2rv (bias init for free) ----
        vacc0 = __builtin_amdgcn_mfma_f32_32x32x16_bf16(thi0[0], a32hi[0], b2rv, 0, 0, 0);
        vacc1 = __builtin_amdgcn_mfma_f32_32x32x16_bf16(thi1[0], a32hi[0], b2rv, 0, 0, 0);
        vacc0 = __builtin_amdgcn_mfma_f32_32x32x16_bf16(thi0[1], a32hi[1], vacc0, 0, 0, 0);
        vacc1 = __builtin_amdgcn_mfma_f32_32x32x16_bf16(thi1[1], a32hi[1], vacc1, 0, 0, 0);

        // ---- epilogues, interleaved (independent shfl chains) ----
        float ss0 = 0.0f, ss1 = 0.0f;
        #pragma unroll
        for (int k = 0; k < 16; k++) {
            ss0 = fmaf(fmaxf(vacc0[k], 0.0f), woutr[k], ss0);
            ss1 = fmaf(fmaxf(vacc1[k], 0.0f), woutr[k], ss1);
        }
        ss0 += __shfl_xor(ss0, 32, 64);
        ss1 += __shfl_xor(ss1, 32, 64);
        float o0 = fmaxf(ss0 + boutv, 0.0f);
        float o1 = fmaxf(ss1 + boutv, 0.0f);
        o0 += __shfl_xor(o0, 1, 64);  o1 += __shfl_xor(o1, 1, 64);
        o0 += __shfl_xor(o0, 2, 64);  o1 += __shfl_xor(o1, 2, 64);
        o0 += __shfl_xor(o0, 4, 64);  o1 += __shfl_xor(o1, 4, 64);
        if (q == 0 && n8 == 0) {
            long long gg0 = gbase + g0;
            if (gg0 < (long long)B) out[gg0] = o0 * 0.125f;
            long long gg1 = gbase + g1;
            if (gg1 < (long long)B) out[gg1] = o1 * 0.125f;
        }
        buf ^= 1;
    }
}

extern "C" void kernel_launch(void* const* d_in, const int* in_sizes, int n_in,
                              void* d_out, int out_size, void* d_ws, size_t ws_size,
                              hipStream_t stream) {
    const float* x    = (const float*)d_in[0];
    const int*   ei   = (const int*)d_in[1];
    const float* W1   = (const float*)d_in[2];
    const float* b1   = (const float*)d_in[3];
    const float* W2   = (const float*)d_in[4];
    const float* b2   = (const float*)d_in[5];
    const float* Wout = (const float*)d_in[6];
    const float* bout = (const float*)d_in[7];
    float* out = (float*)d_out;
    (void)d_ws; (void)ws_size; (void)out_size; (void)n_in;

    const int B = in_sizes[0] / 24;                 // 262144
    const int ntiles = (B + GPT - 1) / GPT;         // 8192
    const int grid = ntiles < 2048 ? ntiles : 2048; // grid-stride, 4 iters/block
    gnn_kernel<<<grid, 256, 0, stream>>>(x, ei, W1, b1, W2, b2, Wout, bout, out, B, ntiles);
}